// Round 10
// baseline (83.647 us; speedup 1.0000x reference)
//
#include <hip/hip_runtime.h>

// Problem constants (match the reference file).
constexpr int DIM = 512;   // irreps dim for x, y, out
constexpr int C   = 16;    // channel multiplicity
constexpr int TPB = 256;   // threads per block (4 waves); 4 blocks/CU
constexpr int USTRIDE = 10;            // uints per LDS row (32 B data + 8 B pad)
constexpr int BUFU = DIM * USTRIDE;    // 5120 uints = 20 KiB per array

// Setup: block 0 builds the balanced plan; blocks >=1 pack pdata.
//   plan[rank] = {seg_start, seg_end, d*C, 0}, ranks by seg length desc.
//   pdata[p] = {i1*USTRIDE, i2*USTRIDE, scale_bits, 0} (uint offsets in LDS).
__global__ __launch_bounds__(1024) void setup_kernel(
    const int* __restrict__ io,
    const int* __restrict__ i1,
    const int* __restrict__ i2,
    const float* __restrict__ scale,
    int4* __restrict__ plan,
    int4* __restrict__ pdata,
    int nnz) {
    if (blockIdx.x == 0) {
        __shared__ int s_start[DIM + 1];
        __shared__ int s_len[DIM];
        const int t = threadIdx.x;
        if (t <= DIM) {
            int lo = 0, hi = nnz;
            while (lo < hi) {
                int mid = (lo + hi) >> 1;
                if (io[mid] < t) lo = mid + 1; else hi = mid;
            }
            s_start[t] = lo;
        }
        __syncthreads();
        if (t < DIM) s_len[t] = s_start[t + 1] - s_start[t];
        __syncthreads();
        if (t < DIM) {
            const int ld = s_len[t];
            int rank = 0;
            #pragma unroll 8
            for (int j = 0; j < DIM; ++j) {
                const int lj = s_len[j];
                rank += (lj > ld) || (lj == ld && j < t);
            }
            plan[rank] = make_int4(s_start[t], s_start[t + 1], t * C, 0);
        }
    } else {
        const int p = (blockIdx.x - 1) * 1024 + threadIdx.x;
        if (p < nnz)
            pdata[p] = make_int4(i1[p] * USTRIDE, i2[p] * USTRIDE,
                                 __float_as_int(scale[p]), 0);
    }
}

// f32 -> packed 2x bf16 (RNE), a in low half, b in high half.
__device__ __forceinline__ unsigned int pk_bf16(float a, float b) {
    unsigned int ua = __float_as_uint(a);
    unsigned int ub = __float_as_uint(b);
    ua = (ua + 0x7FFFu + ((ua >> 16) & 1u)) >> 16;
    ub = (ub + 0x7FFFu + ((ub >> 16) & 1u)) & 0xFFFF0000u;
    return ua | ub;
}

struct Heads { int4 h0, h1, h2, h3; };

__device__ __forceinline__ Heads load_heads(const int4* __restrict__ pdata,
                                            int s, int e) {
    Heads H;
    H.h0 = H.h1 = H.h2 = H.h3 = make_int4(0, 0, 0, 0);
    if (s < e) {
        const int last = e - 1;
        H.h0 = pdata[s];
        H.h1 = pdata[s + 1 < last ? s + 1 : last];
        H.h2 = pdata[s + 2 < last ? s + 2 : last];
        H.h3 = pdata[s + 3 < last ? s + 3 : last];
    }
    return H;
}

// One block per n (2048 blocks, 4 resident/CU).  x,y rows staged in LDS as
// bf16 with 40 B row stride: row starts cycle 16 bank offsets -> staging
// writes exactly uniform, random gather reads ~1.4x b64 floor.  64 4-lane
// groups x 8 serpentine ranks; inner loop: depth-4 pdata / depth-2 LDS
// pipeline; next rank's plan + segment heads prefetched during the current
// rank's loop.  f32 accumulate, f32 out.  No atomics.
__global__ __launch_bounds__(TPB) void tp_kernel(
    const float* __restrict__ x, const float* __restrict__ y,
    const int4* __restrict__ plan,
    const int4* __restrict__ pdata,
    float* __restrict__ out) {
    __shared__ unsigned int xs[BUFU];   // 20 KiB
    __shared__ unsigned int ys[BUFU];   // 20 KiB -> 40 KiB total

    const int n = blockIdx.x;
    const float4* __restrict__ xg = reinterpret_cast<const float4*>(x) + (size_t)n * (DIM * C / 4);
    const float4* __restrict__ yg = reinterpret_cast<const float4*>(y) + (size_t)n * (DIM * C / 4);

    // Stage + convert: global float4 s <-> (row a = s>>2, quad q = s&3);
    // LDS uint2 at a*USTRIDE + q*2.  Coalesced 1 KiB/wave chunks.
    #pragma unroll
    for (int s = threadIdx.x; s < DIM * 4; s += TPB) {   // 8 iterations
        const int slot = (s >> 2) * USTRIDE + (s & 3) * 2;
        const float4 xv = xg[s];
        const float4 yv = yg[s];
        *reinterpret_cast<uint2*>(xs + slot) =
            make_uint2(pk_bf16(xv.x, xv.y), pk_bf16(xv.z, xv.w));
        *reinterpret_cast<uint2*>(ys + slot) =
            make_uint2(pk_bf16(yv.x, yv.y), pk_bf16(yv.z, yv.w));
    }
    __syncthreads();

    const int l4  = threadIdx.x & 3;          // c-quad lane
    const int grp = threadIdx.x >> 2;         // 0..63
    const int cu2 = l4 * 2;                   // uint offset within row
    float* __restrict__ obase = out + (size_t)n * (DIM * C) + l4 * 4;

    // Cross-rank pipeline: plan 2 ahead, heads 1 ahead.
    int4 pl  = plan[grp];                                  // rank(0)
    int4 pln = plan[64 + (63 - grp)];                      // rank(1)
    Heads Hc = load_heads(pdata, pl.x, pl.y);

    #pragma unroll
    for (int k = 0; k < 8; ++k) {
        const int rnn = (k + 2 < 8)
            ? ((k + 2) << 6) + (((k + 2) & 1) ? (63 - grp) : grp) : 0;
        const int4 plnn = plan[rnn];                       // rank(k+2) (or dummy)
        const Heads Hn = (k + 1 < 8) ? load_heads(pdata, pln.x, pln.y) : Hc;

        const int s = pl.x, e = pl.y;
        float ax = 0.f, ay = 0.f, az = 0.f, aw = 0.f;
        if (s < e) {
            const int last = e - 1;
            uint2 xv0 = *reinterpret_cast<const uint2*>(xs + Hc.h0.x + cu2);
            uint2 yv0 = *reinterpret_cast<const uint2*>(ys + Hc.h0.y + cu2);
            uint2 xv1 = *reinterpret_cast<const uint2*>(xs + Hc.h1.x + cu2);
            uint2 yv1 = *reinterpret_cast<const uint2*>(ys + Hc.h1.y + cu2);
            float s0 = __int_as_float(Hc.h0.z);
            float s1 = __int_as_float(Hc.h1.z);
            int4 q2 = Hc.h2, q3 = Hc.h3;
            for (int p = s; p < e; ++p) {
                const int4 q4 = pdata[p + 4 < last ? p + 4 : last];
                const uint2 xv2 = *reinterpret_cast<const uint2*>(xs + q2.x + cu2);
                const uint2 yv2 = *reinterpret_cast<const uint2*>(ys + q2.y + cu2);
                const float x0 = __uint_as_float(xv0.x << 16);
                const float x1 = __uint_as_float(xv0.x & 0xFFFF0000u);
                const float x2 = __uint_as_float(xv0.y << 16);
                const float x3 = __uint_as_float(xv0.y & 0xFFFF0000u);
                const float y0 = __uint_as_float(yv0.x << 16);
                const float y1 = __uint_as_float(yv0.x & 0xFFFF0000u);
                const float y2 = __uint_as_float(yv0.y << 16);
                const float y3 = __uint_as_float(yv0.y & 0xFFFF0000u);
                ax = fmaf(s0 * x0, y0, ax);
                ay = fmaf(s0 * x1, y1, ay);
                az = fmaf(s0 * x2, y2, az);
                aw = fmaf(s0 * x3, y3, aw);
                s0 = s1; s1 = __int_as_float(q2.z);
                q2 = q3; q3 = q4;
                xv0 = xv1; yv0 = yv1; xv1 = xv2; yv1 = yv2;
            }
        }
        *reinterpret_cast<float4*>(obase + pl.z) = make_float4(ax, ay, az, aw);

        pl = pln; pln = plnn; Hc = Hn;
    }
}

extern "C" void kernel_launch(void* const* d_in, const int* in_sizes, int n_in,
                              void* d_out, int out_size, void* d_ws, size_t ws_size,
                              hipStream_t stream) {
    const float* x     = (const float*)d_in[0];
    const float* y     = (const float*)d_in[1];
    const float* scale = (const float*)d_in[2];
    const int*   i1    = (const int*)d_in[3];
    const int*   i2    = (const int*)d_in[4];
    const int*   io    = (const int*)d_in[5];
    float* out = (float*)d_out;

    const int nnz = in_sizes[2];
    const int N   = in_sizes[0] / (DIM * C);

    int4* plan  = (int4*)d_ws;                       // DIM int4s (8 KiB)
    int4* pdata = (int4*)((char*)d_ws + 8192);       // nnz int4s (64 KiB)

    const int pack_blocks = (nnz + 1023) / 1024;
    setup_kernel<<<1 + pack_blocks, 1024, 0, stream>>>(io, i1, i2, scale, plan, pdata, nnz);
    tp_kernel<<<N, TPB, 0, stream>>>(x, y, plan, pdata, out);
}